// Round 1
// baseline (542.664 us; speedup 1.0000x reference)
//
#include <hip/hip_runtime.h>

#define BB     128
#define MM     4096
#define NN     8192
#define DEG    12
#define MAXIT  8
#define NEXT   (NN + 1)
#define BLOCK  1024
#define RPT    (MM / BLOCK)   // 4 rows per thread

// fp2fxp with int_width=3, frac_width=4: scale=16, qmax=127/16, qmin=-128/16.
// jnp.round is round-half-to-even -> rintf (v_rndne_f32).
__device__ __forceinline__ float fxp(float x) {
    float r = rintf(x * 16.0f);
    r = fminf(r, 127.0f);
    r = fmaxf(r, -128.0f);
    return r * 0.0625f;
}

#define LOAD_COLS(row)                                                        \
    const int4* cp = (const int4*)(Vcol + (size_t)(row) * DEG);               \
    int4 c0 = cp[0], c1 = cp[1], c2 = cp[2];                                  \
    const int cols[DEG] = {c0.x, c0.y, c0.z, c0.w,                            \
                           c1.x, c1.y, c1.z, c1.w,                            \
                           c2.x, c2.y, c2.z, c2.w};

__global__ __launch_bounds__(BLOCK, 1)
void ldpc_kernel(const float* __restrict__ synd,
                 const float* __restrict__ llr0,
                 const int*  __restrict__ Vcol,
                 float* __restrict__ out)
{
    __shared__ float lv[NEXT];   // 32772 B
    __shared__ int   flag;

    const int b   = blockIdx.x;
    const int tid = threadIdx.x;
    const float* llr_b  = llr0 + (size_t)b * NN;
    const float* synd_b = synd + (size_t)b * MM;

    // message init: msg[k][d] = u_init[col] (u_init = fxp(llr0), dummy = +inf)
    float msg[RPT][DEG];
    #pragma unroll
    for (int k = 0; k < RPT; ++k) {
        const int row = tid + k * BLOCK;
        LOAD_COLS(row);
        #pragma unroll
        for (int d = 0; d < DEG; ++d) {
            msg[k][d] = (cols[d] < NN) ? fxp(llr_b[cols[d]]) : __builtin_inff();
        }
    }

    int conv_it = 0;  // 0 = not converged yet

    for (int it = 1; it <= MAXIT; ++it) {
        // fp2fxp(1 - 2^-it), precomputed (RNE: i>=5 rounds to 1.0)
        const float fb = (it == 1) ? 0.5f
                       : (it == 2) ? 0.75f
                       : (it == 3) ? 0.875f
                       : (it == 4) ? 0.9375f
                       : 1.0f;

        // ---- phase 1: a_v2c -> b_c2v (stored back into msg) ----
        #pragma unroll
        for (int k = 0; k < RPT; ++k) {
            const int row = tid + k * BLOCK;
            LOAD_COLS(row);
            float a[DEG];
            #pragma unroll
            for (int d = 0; d < DEG; ++d) {
                // it==1: a = message0 (already quantized / inf at dummy)
                a[d] = (it == 1) ? msg[k][d] : fxp(lv[cols[d]] - msg[k][d]);
            }
            float min0 = __builtin_inff(), min1 = __builtin_inff();
            int negs = 0;
            #pragma unroll
            for (int d = 0; d < DEG; ++d) {
                float aa = fabsf(a[d]);
                negs ^= (a[d] <= 0.0f) ? 1 : 0;   // sign(0) -> -1 per reference
                if (aa < min0)      { min1 = min0; min0 = aa; }
                else if (aa < min1) { min1 = aa; }
            }
            const float syn = synd_b[row];
            const float qs  = ((syn == 0.0f) ? 1.0f : -1.0f) * (negs ? -1.0f : 1.0f);
            #pragma unroll
            for (int d = 0; d < DEG; ++d) {
                float aa = fabsf(a[d]);
                float mr = (aa == min0) ? min1 : min0;
                float q  = fxp(fb * fxp(mr));            // magnitude, sign applied below
                float sg = (a[d] > 0.0f) ? 1.0f : -1.0f;
                float bb = sg * qs * q;
                msg[k][d] = (cols[d] < NN) ? bb : 0.0f;  // dummy edge -> 0
            }
        }
        __syncthreads();

        // ---- phase 2: reset l_v = u_init ----
        for (int n = tid; n < NN; n += BLOCK) lv[n] = fxp(llr_b[n]);
        if (tid == 0) { lv[NN] = __builtin_inff(); flag = 0; }
        __syncthreads();

        // ---- phase 3: scatter-add b_c2v (exact: multiples of 1/16) ----
        #pragma unroll
        for (int k = 0; k < RPT; ++k) {
            const int row = tid + k * BLOCK;
            LOAD_COLS(row);
            #pragma unroll
            for (int d = 0; d < DEG; ++d) {
                if (cols[d] < NN) atomicAdd(&lv[cols[d]], msg[k][d]);
            }
        }
        __syncthreads();

        // ---- phase 4: parity + convergence check ----
        int mism = 0;
        #pragma unroll
        for (int k = 0; k < RPT; ++k) {
            const int row = tid + k * BLOCK;
            LOAD_COLS(row);
            int par = 0;
            #pragma unroll
            for (int d = 0; d < DEG; ++d) {
                // e_v = (fxp(lv) <= 0); lv is a multiple of 1/16 so == (lv <= 0).
                // dummy col: lv[NN] = +inf -> contributes 0.
                par ^= (lv[cols[d]] <= 0.0f) ? 1 : 0;
            }
            const float syn = synd_b[row];
            mism |= (par != ((syn != 0.0f) ? 1 : 0));
        }
        if (mism) atomicOr(&flag, 1);
        __syncthreads();
        if (flag == 0) { conv_it = it; break; }   // uniform branch (shared flag)
    }

    // ---- outputs: [e_out | num_iters | l_out | converges], float32 flat ----
    const int   it_out = conv_it ? conv_it : MAXIT;
    const float cv     = conv_it ? 1.0f : 0.0f;
    float* e_out   = out;
    float* num_out = out + (size_t)BB * NN;
    float* l_out   = num_out + BB;
    float* c_out   = l_out + (size_t)BB * NN;
    for (int n = tid; n < NN; n += BLOCK) {
        float v = lv[n];
        e_out[(size_t)b * NN + n] = (v <= 0.0f) ? 1.0f : 0.0f;
        l_out[(size_t)b * NN + n] = fxp(v);
    }
    if (tid == 0) { num_out[b] = (float)it_out; c_out[b] = cv; }
}

extern "C" void kernel_launch(void* const* d_in, const int* in_sizes, int n_in,
                              void* d_out, int out_size, void* d_ws, size_t ws_size,
                              hipStream_t stream) {
    (void)in_sizes; (void)n_in; (void)d_ws; (void)ws_size; (void)out_size;
    const float* synd = (const float*)d_in[0];
    const float* llr0 = (const float*)d_in[1];
    const int*   Vcol = (const int*)d_in[3];   // V_c_col
    float*       out  = (float*)d_out;
    ldpc_kernel<<<BB, BLOCK, 0, stream>>>(synd, llr0, Vcol, out);
}

// Round 2
// 254.117 us; speedup vs baseline: 2.1355x; 2.1355x over previous
//
#include <hip/hip_runtime.h>

#define BB     128
#define MM     4096
#define NN     8192
#define DEG    12
#define MAXIT  8
#define BLOCK  1024
#define RPT    (MM / BLOCK)   // 4 rows per thread
#define NP     (DEG / 2)      // 6 packed column-pairs per row
#define BIGA   (1 << 20)      // "infinity" for the dummy edge at it==1

__device__ __forceinline__ int clamp8(int t) {
    return max(-128, min(127, t));
}

// All LLR state in fixed-point integers (units of 1/16). Exact, order-independent.
__global__ __launch_bounds__(BLOCK, 4)
void ldpc_kernel(const float* __restrict__ synd,
                 const float* __restrict__ llr0,
                 const int*  __restrict__ Vcol,
                 float* __restrict__ out)
{
    __shared__ int lvI[NN];     // 32 KB
    __shared__ int lastbad;     // max iteration index with a parity mismatch

    const int b   = blockIdx.x;
    const int tid = threadIdx.x;
    const float* llr_b  = llr0 + (size_t)b * NN;
    const float* synd_b = synd + (size_t)b * MM;

    // ---- cache columns (2 x u16 per reg) and syndrome bits in registers ----
    unsigned colp[RPT][NP];
    int      syn[RPT];
    #pragma unroll
    for (int k = 0; k < RPT; ++k) {
        const int row = tid + k * BLOCK;
        const int4* cp = (const int4*)(Vcol + (size_t)row * DEG);
        int4 c0 = cp[0], c1 = cp[1], c2 = cp[2];
        const int cc[DEG] = {c0.x,c0.y,c0.z,c0.w,c1.x,c1.y,c1.z,c1.w,
                             c2.x,c2.y,c2.z,c2.w};
        #pragma unroll
        for (int p = 0; p < NP; ++p)
            colp[k][p] = ((unsigned)cc[2*p] & 0xffffu) | ((unsigned)cc[2*p+1] << 16);
        syn[k] = (synd_b[row] != 0.0f) ? 1 : 0;
    }

    // ---- init lvI = u0 (quantized llr), RNE once here ----
    #pragma unroll
    for (int j = 0; j < NN / BLOCK; ++j) {
        const int n = tid + j * BLOCK;
        float r = rintf(llr_b[n] * 16.0f);
        r = fminf(r, 127.0f);
        r = fmaxf(r, -128.0f);
        lvI[n] = (int)r;
    }
    if (tid == 0) lastbad = 1;

    unsigned msgp[RPT][NP];   // current edge messages b (2 x s16 per reg)
    unsigned dltp[RPT][NP];   // per-iteration deltas b_new - b_old
    #pragma unroll
    for (int k = 0; k < RPT; ++k)
        #pragma unroll
        for (int p = 0; p < NP; ++p) msgp[k][p] = 0;

    __syncthreads();

    int conv_it = 0;
    int it = 1;
    for (; it <= MAXIT; ++it) {
        const float fb  = (it==1)?0.5f:(it==2)?0.75f:(it==3)?0.875f:0.9375f;
        const bool  fb1 = (it >= 5);   // fp2fxp(beta) rounds to 1.0
        int mism = 0;

        // ---- phase 1: gather lv, parity(prev iter), min-sum, compute deltas ----
        #pragma unroll
        for (int k = 0; k < RPT; ++k) {
            int a[DEG];
            int par = 0;
            #pragma unroll
            for (int d = 0; d < DEG; ++d) {
                const unsigned cw = colp[k][d >> 1];
                const int col = (int)((d & 1) ? (cw >> 16) : (cw & 0xffffu));
                const bool real = col < NN;
                const int l = lvI[real ? col : 0];
                const unsigned mw = msgp[k][d >> 1];
                const int m = (d & 1) ? ((int)mw >> 16) : (int)(short)(mw & 0xffffu);
                par ^= (real && l <= 0) ? 1 : 0;
                const int t = clamp8(l - m);   // a at it==1: m==0, lv==u0 -> exact
                a[d] = real ? t : ((it == 1) ? BIGA : 127);  // fxp(inf-0)=7.9375
            }
            mism |= (par ^ syn[k]);
            int min0 = BIGA, min1 = BIGA, negs = 0;
            #pragma unroll
            for (int d = 0; d < DEG; ++d) {
                const int aa = abs(a[d]);
                negs ^= (a[d] <= 0) ? 1 : 0;       // sign(0) -> -1 per reference
                min1 = min(min1, max(min0, aa));
                min0 = min(min0, aa);
            }
            const int qsb = syn[k] ^ negs;         // 1 => flip sign
            #pragma unroll
            for (int d = 0; d < DEG; ++d) {
                const unsigned cw = colp[k][d >> 1];
                const int col = (int)((d & 1) ? (cw >> 16) : (cw & 0xffffu));
                const bool real = col < NN;
                const int aa = abs(a[d]);
                const int mr = (aa == min0) ? min1 : min0;
                const int q  = fb1 ? mr : (int)rintf(fb * (float)mr);  // RNE, <=127
                const int sg = ((a[d] <= 0) ? 1 : 0) ^ qsb;
                int bI = sg ? -q : q;
                if (!real) bI = 0;
                const unsigned mw = msgp[k][d >> 1];
                const int mold = (d & 1) ? ((int)mw >> 16) : (int)(short)(mw & 0xffffu);
                const int dl = bI - mold;
                if (d & 1) {
                    msgp[k][d>>1] = (mw & 0x0000ffffu) | ((unsigned)bI << 16);
                    dltp[k][d>>1] = (dltp[k][d>>1] & 0x0000ffffu) | ((unsigned)dl << 16);
                } else {
                    msgp[k][d>>1] = (mw & 0xffff0000u) | ((unsigned)bI & 0xffffu);
                    dltp[k][d>>1] = ((unsigned)dl & 0xffffu);
                }
            }
        }
        if (it >= 2) {
            if (__any(mism) && (tid & 63) == 0) atomicMax(&lastbad, it);
        }
        __syncthreads();                      // gathers done + lastbad settled
        if (it >= 2 && lastbad < it) { conv_it = it - 1; break; }

        // ---- phase 2: delta scatter (zero deltas skipped) ----
        #pragma unroll
        for (int k = 0; k < RPT; ++k) {
            #pragma unroll
            for (int d = 0; d < DEG; ++d) {
                const unsigned cw = colp[k][d >> 1];
                const int col = (int)((d & 1) ? (cw >> 16) : (cw & 0xffffu));
                const unsigned dw = dltp[k][d >> 1];
                const int dl = (d & 1) ? ((int)dw >> 16) : (int)(short)(dw & 0xffffu);
                if (col < NN && dl != 0) atomicAdd(&lvI[col], dl);
            }
        }
        __syncthreads();                      // scatter done before next gather
    }

    // ---- final parity for iteration 8 if never converged ----
    if (it > MAXIT) {
        int mism = 0;
        #pragma unroll
        for (int k = 0; k < RPT; ++k) {
            int par = 0;
            #pragma unroll
            for (int d = 0; d < DEG; ++d) {
                const unsigned cw = colp[k][d >> 1];
                const int col = (int)((d & 1) ? (cw >> 16) : (cw & 0xffffu));
                const bool real = col < NN;
                const int l = lvI[real ? col : 0];
                par ^= (real && l <= 0) ? 1 : 0;
            }
            mism |= (par ^ syn[k]);
        }
        if (__any(mism) && (tid & 63) == 0) atomicMax(&lastbad, MAXIT + 1);
        __syncthreads();
        if (lastbad < MAXIT + 1) conv_it = MAXIT;
    }

    // ---- outputs: [e_out | num_iters | l_out | converges], float32 flat ----
    const int   num = conv_it ? conv_it : MAXIT;
    const float cv  = conv_it ? 1.0f : 0.0f;
    float* e_out   = out;
    float* num_out = out + (size_t)BB * NN;
    float* l_out   = num_out + BB;
    float* c_out   = l_out + (size_t)BB * NN;
    #pragma unroll
    for (int j = 0; j < NN / BLOCK; ++j) {
        const int n = tid + j * BLOCK;
        const int l = lvI[n];
        e_out[(size_t)b * NN + n] = (l <= 0) ? 1.0f : 0.0f;
        l_out[(size_t)b * NN + n] = (float)clamp8(l) * 0.0625f;
    }
    if (tid == 0) { num_out[b] = (float)num; c_out[b] = cv; }
}

extern "C" void kernel_launch(void* const* d_in, const int* in_sizes, int n_in,
                              void* d_out, int out_size, void* d_ws, size_t ws_size,
                              hipStream_t stream) {
    (void)in_sizes; (void)n_in; (void)d_ws; (void)ws_size; (void)out_size;
    const float* synd = (const float*)d_in[0];
    const float* llr0 = (const float*)d_in[1];
    const int*   Vcol = (const int*)d_in[3];   // V_c_col
    float*       out  = (float*)d_out;
    ldpc_kernel<<<BB, BLOCK, 0, stream>>>(synd, llr0, Vcol, out);
}

// Round 3
// 138.138 us; speedup vs baseline: 3.9284x; 1.8396x over previous
//
#include <hip/hip_runtime.h>

#define BB     128
#define MM     4096
#define NN     8192
#define DEG    12
#define RDEG   11          // edges 0..10 are real; edge 11 is ALWAYS the dummy (col==NN)
#define MAXIT  8
#define BLOCK  1024
#define RPT    (MM / BLOCK)
#define NW     (NN / 2)    // l_v packed: 2 vars per 32-bit word, u16 halves biased +32768
#define BIAS   32768

__device__ __forceinline__ int quantI(float x) {   // fp2fxp -> integer units of 1/16
    float r = rintf(x * 16.0f);                    // RNE, matches jnp.round
    r = fminf(r, 127.0f);
    r = fmaxf(r, -128.0f);
    return (int)r;
}

__device__ __forceinline__ int clamp8(int t) { return max(-128, min(127, t)); }

__global__ __launch_bounds__(BLOCK, 4)
__attribute__((amdgpu_waves_per_eu(4, 4)))
void ldpc_kernel(const float* __restrict__ synd,
                 const float* __restrict__ llr0,
                 const int*  __restrict__ Vcol,
                 float* __restrict__ out)
{
    __shared__ int lvbuf[3][NW];   // 48 KB: cur / nxt / rst rotation
    __shared__ int lastbad;

    const int b   = blockIdx.x;
    const int tid = threadIdx.x;
    const float* llr_b  = llr0 + (size_t)b * NN;
    const float* synd_b = synd + (size_t)b * MM;

    // ---- persistent register state ----
    unsigned colp[RPT][6];    // 11 cols packed 2 x u16 (high half of [5] unused)
    unsigned msgp[RPT][3];    // 11 messages packed s8 (byte 3 of [2] unused)
    int u0w[4];               // packed biased u0 pairs for buffer reset
    int synbits = 0;

    #pragma unroll
    for (int k = 0; k < RPT; ++k) {
        const int row = tid + k * BLOCK;
        const int4* cp = (const int4*)(Vcol + (size_t)row * DEG);
        int4 c0 = cp[0], c1 = cp[1], c2 = cp[2];
        const int cc[RDEG] = {c0.x,c0.y,c0.z,c0.w,c1.x,c1.y,c1.z,c1.w,c2.x,c2.y,c2.z};
        #pragma unroll
        for (int p = 0; p < 5; ++p)
            colp[k][p] = (unsigned)cc[2*p] | ((unsigned)cc[2*p+1] << 16);
        colp[k][5] = (unsigned)cc[10];
        synbits |= ((synd_b[row] != 0.0f) ? 1 : 0) << k;
    }

    // ---- init: buffer1 = u0 (scatter target of iter 1); msg = u0[col] via global gather
    #pragma unroll
    for (int j = 0; j < 4; ++j) {
        const int w = tid + j * BLOCK;
        float2 f = ((const float2*)llr_b)[w];
        u0w[j] = (quantI(f.x) + BIAS) | ((quantI(f.y) + BIAS) << 16);
        lvbuf[1][w] = u0w[j];
    }
    if (tid == 0) lastbad = 1;
    #pragma unroll
    for (int k = 0; k < RPT; ++k) {
        unsigned nm[3] = {0u, 0u, 0u};
        #pragma unroll
        for (int d = 0; d < RDEG; ++d) {
            const int col = (int)((colp[k][d >> 1] >> ((d & 1) * 16)) & 0xffffu);
            const int m = quantI(llr_b[col]);          // one-time, L1/L2-resident gather
            nm[d >> 2] |= ((unsigned)m & 0xffu) << ((d & 3) * 8);
        }
        msgp[k][0] = nm[0]; msgp[k][1] = nm[1]; msgp[k][2] = nm[2];
    }
    __syncthreads();

    int* cur = lvbuf[0];   // unused at it==1
    int* nxt = lvbuf[1];   // holds u0
    int* rst = lvbuf[2];

    int conv_it = 0;
    int it = 1;
    for (; it <= MAXIT; ++it) {
        const int  fbI = (it==1) ? 8 : (it==2) ? 12 : (it==3) ? 14 : 15;
        const bool fb1 = (it >= 5);    // fp2fxp(beta) == 1.0
        int mism = 0;

        #pragma unroll
        for (int k = 0; k < RPT; ++k) {
            unsigned aap[3] = {0u, 0u, 0u};   // |a| packed u8 (<=128 fits a byte)
            int sbits = 0;                     // bit d: a[d] <= 0
            int min0 = 1 << 20, min1 = 1 << 20;
            int par = 0;
            #pragma unroll
            for (int d = 0; d < RDEG; ++d) {
                const int col = (int)((colp[k][d >> 1] >> ((d & 1) * 16)) & 0xffffu);
                const int m = (int)(signed char)((msgp[k][d >> 2] >> ((d & 3) * 8)) & 0xffu);
                int aval;
                if (it == 1) {
                    aval = m;                              // a = message0
                } else {
                    const int w = cur[col >> 1];
                    const int l = (int)((w >> ((col & 1) << 4)) & 0xffff) - BIAS;
                    par ^= (l <= 0) ? 1 : 0;               // parity of l_v(it-1)
                    aval = clamp8(l - m);
                }
                const int aa = abs(aval);
                sbits |= ((aval <= 0) ? 1 : 0) << d;       // sign(0) -> -1
                min1 = min(min1, max(min0, aa));
                min0 = min(min0, aa);
                aap[d >> 2] |= (unsigned)aa << ((d & 3) * 8);
            }
            if (it > 1) {
                // dummy edge: a = fxp(inf - 0) = 7.9375 -> 127, sign +, participates in mins
                min1 = min(min1, max(min0, 127));
                min0 = min(min0, 127);
                mism |= par ^ ((synbits >> k) & 1);
            }
            // (it==1: dummy a = +inf -> no min participation, sign +)
            const int negs = __popc(sbits) & 1;
            const int qsb  = ((synbits >> k) & 1) ^ negs;  // 1 => flip sign

            unsigned nm[3] = {0u, 0u, 0u};
            #pragma unroll
            for (int d = 0; d < RDEG; ++d) {
                const int aa = (int)((aap[d >> 2] >> ((d & 3) * 8)) & 0xffu);
                const int mr = (aa == min0) ? min1 : min0;
                const int mrC = min(mr, 127);              // fp2fxp(min_res) clamp
                int q;
                if (fb1) {
                    q = mrC;
                } else {                                    // RNE of mrC*fbI/16
                    const int t = mrC * fbI;
                    const int r = t >> 4, rem = t & 15;
                    q = r + (((rem > 8) || (rem == 8 && (r & 1))) ? 1 : 0);
                }
                const int s = ((sbits >> d) & 1) ^ qsb;
                const int bv = s ? -q : q;
                nm[d >> 2] |= ((unsigned)bv & 0xffu) << ((d & 3) * 8);
                const int col = (int)((colp[k][d >> 1] >> ((d & 1) * 16)) & 0xffffu);
                const int add = (int)((unsigned)bv << ((col & 1) << 4));
                atomicAdd(&nxt[col >> 1], add);            // exact packed-halves add
            }
            msgp[k][0] = nm[0]; msgp[k][1] = nm[1]; msgp[k][2] = nm[2];
        }

        if (it >= 2) {
            if (__any(mism) && (tid & 63) == 0) atomicMax(&lastbad, it);
        }
        // reset rst -> u0 for the scatter two iterations from now
        #pragma unroll
        for (int j = 0; j < 4; ++j) rst[tid + j * BLOCK] = u0w[j];

        __syncthreads();
        if (it >= 2 && lastbad < it) { conv_it = it - 1; break; }  // cur == l_v(it-1)

        int* t = cur; cur = nxt; nxt = rst; rst = t;       // rotate
    }

    // ---- if loop ran to completion, check parity of l_v(8) (now in cur) ----
    if (conv_it == 0) {
        int mism = 0;
        #pragma unroll
        for (int k = 0; k < RPT; ++k) {
            int par = 0;
            #pragma unroll
            for (int d = 0; d < RDEG; ++d) {
                const int col = (int)((colp[k][d >> 1] >> ((d & 1) * 16)) & 0xffffu);
                const int w = cur[col >> 1];
                const int l = (int)((w >> ((col & 1) << 4)) & 0xffff) - BIAS;
                par ^= (l <= 0) ? 1 : 0;
            }
            mism |= par ^ ((synbits >> k) & 1);
        }
        if (__any(mism) && (tid & 63) == 0) atomicMax(&lastbad, MAXIT + 1);
        __syncthreads();
        if (lastbad < MAXIT + 1) conv_it = MAXIT;
    }

    // ---- outputs: [e_out | num_iters | l_out | converges], float32 flat ----
    const int   num = conv_it ? conv_it : MAXIT;
    const float cv  = conv_it ? 1.0f : 0.0f;
    float* e_out   = out;
    float* num_out = out + (size_t)BB * NN;
    float* l_out   = num_out + BB;
    float* c_out   = l_out + (size_t)BB * NN;
    #pragma unroll
    for (int j = 0; j < 4; ++j) {
        const int w = tid + j * BLOCK;
        const int wv = cur[w];
        const int l0 = (wv & 0xffff) - BIAS;
        const int l1 = ((wv >> 16) & 0xffff) - BIAS;
        float2 e, l;
        e.x = (l0 <= 0) ? 1.0f : 0.0f;
        e.y = (l1 <= 0) ? 1.0f : 0.0f;
        l.x = (float)clamp8(l0) * 0.0625f;
        l.y = (float)clamp8(l1) * 0.0625f;
        ((float2*)(e_out + (size_t)b * NN))[w] = e;
        ((float2*)(l_out + (size_t)b * NN))[w] = l;
    }
    if (tid == 0) { num_out[b] = (float)num; c_out[b] = cv; }
}

extern "C" void kernel_launch(void* const* d_in, const int* in_sizes, int n_in,
                              void* d_out, int out_size, void* d_ws, size_t ws_size,
                              hipStream_t stream) {
    (void)in_sizes; (void)n_in; (void)d_ws; (void)ws_size; (void)out_size;
    const float* synd = (const float*)d_in[0];
    const float* llr0 = (const float*)d_in[1];
    const int*   Vcol = (const int*)d_in[3];   // V_c_col
    float*       out  = (float*)d_out;
    ldpc_kernel<<<BB, BLOCK, 0, stream>>>(synd, llr0, Vcol, out);
}